// Round 12
// baseline (132.161 us; speedup 1.0000x reference)
//
#include <hip/hip_runtime.h>

typedef _Float16 f16x8 __attribute__((ext_vector_type(8)));
typedef float f32x4 __attribute__((ext_vector_type(4)));

#define N_IMP 300000
#define N_ATOMS 100000
#define NT16 (N_IMP / 16)        // 18750 16-row tiles
#define AT_TILES (N_ATOMS / 16)  // 6250
#define NBLK9 512                // janossy9 blocks (2 per CU)
#define NBEATS9 42               // 37 tiles + 3 pipeline + round to x3
#define NBLKA 512                // atom_gemm4 blocks; 2 tile-pairs each

__device__ __forceinline__ unsigned short f2h(float f) {
  _Float16 h = (_Float16)f;  // v_cvt_f16_f32, RNE
  return __builtin_bit_cast(unsigned short, h);
}
__device__ __forceinline__ unsigned int pk2(float a, float b) {
  return (unsigned int)f2h(a) | ((unsigned int)f2h(b) << 16);
}

// Packed f16 weights in d_ws (ushort units):
//  [0,16384)      Wa  [n][k]  = W1[0:128] + W1[256:384] + W1[384:512]
//  [16384,32768)  Wb  [n][k]  = 3*W1[128:256]
//  [32768,49152)  W2p [n][k]
//  [49152,65536)  W3p [n][k]
//  [65536,67584)  Wop [16][128] (cols 6..15 zero)
//  [67584,67712)  b1 as f16 (128)
//  [67712, +25.6M) uv [atom][256] f16: u = h@Wa (0:128), v = h@Wb (128:256)
#define PB1 67584
#define UV_OFF 67712
#define WS_NEED (2ull * (UV_OFF + (unsigned long long)N_ATOMS * 256))

__global__ __launch_bounds__(256) void prep_kernel(
    const float* __restrict__ W1, const float* __restrict__ W2,
    const float* __restrict__ W3, const float* __restrict__ Wo,
    const float* __restrict__ b1, unsigned short* __restrict__ P) {
  int t = blockIdx.x * 256 + threadIdx.x;  // grid 265 blocks = 67840 threads
  if (t >= UV_OFF) return;
  float v;
  if (t < 16384) {
    int n = t >> 7, k = t & 127;
    v = W1[k * 128 + n] + W1[(k + 256) * 128 + n] + W1[(k + 384) * 128 + n];
  } else if (t < 32768) {
    int i = t - 16384; int n = i >> 7, k = i & 127;
    v = 3.0f * W1[(k + 128) * 128 + n];
  } else if (t < 49152) {
    int i = t - 32768; int n = i >> 7, k = i & 127;
    v = W2[k * 128 + n];
  } else if (t < 65536) {
    int i = t - 49152; int n = i >> 7, k = i & 127;
    v = W3[k * 128 + n];
  } else if (t < PB1) {
    int i = t - 65536; int n = i >> 7, k = i & 127;
    v = (n < 6) ? Wo[k * 6 + n] : 0.0f;
  } else {
    v = b1[t - PB1];
  }
  P[t] = f2h(v);
}

// XOR-swizzled row layout, stride 256 B (G4: row-major 256B-stride f16 is a
// 16-way bank conflict on ds_read_b128 without it). Involution on writer side
// (pre-swizzled global source for gathers / swizzled ds_write) and reader
// side (rule #21). XOR of bit 4 preserves 16B alignment.
__device__ __forceinline__ int swz_off(int row, int kbyte) {
  return (row * 256 + kbyte) ^ ((row & 7) << 4);
}
__device__ __forceinline__ f16x8 lds_frag(const unsigned short* buf, int row, int k0) {
  return *(const f16x8*)((const char*)buf + swz_off(row, k0 * 2));
}
__device__ __forceinline__ void lds_st1(unsigned short* buf, int row, int col, unsigned short v) {
  *(unsigned short*)((char*)buf + swz_off(row, col * 2)) = v;
}
__device__ __forceinline__ void wave_lds_fence() {
  asm volatile("s_waitcnt lgkmcnt(0)" ::: "memory");
}
// Direct global->LDS (no VGPR round-trip). LDS dest = wave-uniform base +
// lane*16; global src is per-lane.
__device__ __forceinline__ void gload16(const void* g, void* l) {
  __builtin_amdgcn_global_load_lds(
      (const __attribute__((address_space(1))) unsigned int*)g,
      (__attribute__((address_space(3))) unsigned int*)l, 16, 0, 0);
}

// ======== atom precompute v4: uv = [h@Wa | h@Wb], weights in REGISTERS ========
// R12 change: loop-top wait vmcnt(4) (not 0) -> the 4 trailing uv stores of
// tile t overlap tile t+1's compute (order: ldh(t+1):8 issued BEFORE stores(t):4,
// so vmcnt(4) drains exactly the loads).
__global__ __launch_bounds__(256, 2) void atom_gemm4(
    const float* __restrict__ h, const unsigned short* __restrict__ P,
    unsigned short* __restrict__ uv) {
  __shared__ __attribute__((aligned(16))) unsigned short Tb[4][2048];  // 4 KB/wave
  const int lane = threadIdx.x & 63;
  const int wid = threadIdx.x >> 6;
  const int col = lane & 15, hi = lane >> 4;
  const int p = wid & 1;  // feature half
  unsigned short* T = Tb[wid];

  // loop-invariant A-frags: feats (p*8+n)*16+col, k = ks*32+hi*8
  f16x8 wfa[32];
#pragma unroll
  for (int n = 0; n < 8; ++n)
#pragma unroll
    for (int ks = 0; ks < 4; ++ks)
      wfa[n * 4 + ks] =
          *(const f16x8*)(P + ((p * 8 + n) * 16 + col) * 128 + ks * 32 + hi * 8);

  float4 hv[8];
  auto ldh = [&](int tt) {
    const float4* phv = (const float4*)(h + (long)(tt * 16 + col) * 128);
#pragma unroll
    for (int ks = 0; ks < 4; ++ks) {
      hv[ks * 2]     = phv[ks * 8 + hi * 2];
      hv[ks * 2 + 1] = phv[ks * 8 + hi * 2 + 1];
    }
  };

  int t = blockIdx.x * 2 + (wid >> 1);  // tile id, stride NBLKA*2 = 1024
  ldh(t);
  asm volatile("s_waitcnt vmcnt(0)" ::: "memory");  // prologue: hv(t0) landed
  for (;;) {
    const int tn = t + NBLKA * 2;
    const bool hn = (tn < AT_TILES);  // wave-uniform
    __builtin_amdgcn_sched_barrier(0);
    f16x8 bfr[4];
#pragma unroll
    for (int ks = 0; ks < 4; ++ks) {
      float4 v0 = hv[ks * 2], v1 = hv[ks * 2 + 1];
      f16x8 b;
      b[0] = (_Float16)v0.x; b[1] = (_Float16)v0.y; b[2] = (_Float16)v0.z; b[3] = (_Float16)v0.w;
      b[4] = (_Float16)v1.x; b[5] = (_Float16)v1.y; b[6] = (_Float16)v1.z; b[7] = (_Float16)v1.w;
      bfr[ks] = b;
    }
    if (hn) ldh(tn);  // fly under MFMA + transpose + store

    f32x4 acc[8] = {};
#pragma unroll
    for (int ks = 0; ks < 4; ++ks)
#pragma unroll
      for (int n = 0; n < 8; ++n)
        acc[n] = __builtin_amdgcn_mfma_f32_16x16x32_f16(wfa[n * 4 + ks], bfr[ks],
                                                        acc[n], 0, 0, 0);

    // transpose: D(col=atom, feat=n*16+hi*4+r) -> T[atom][128 feats-half],
    // row stride 256 B, XOR bit4..6 with atom&7 (8B writes -> 2-way max).
#pragma unroll
    for (int n = 0; n < 8; ++n) {
      uint2 w; w.x = pk2(acc[n][0], acc[n][1]); w.y = pk2(acc[n][2], acc[n][3]);
      int bo_ = (col * 256 + n * 32 + hi * 8) ^ ((col & 7) << 4);
      *(uint2*)((char*)T + bo_) = w;
    }
    wave_lds_fence();
    // readback linear (same involution) -> 256 B contiguous per atom-half
    char* dst = (char*)uv + (long)t * 16 * 512 + p * 256;
#pragma unroll
    for (int i = 0; i < 4; ++i) {
      int c2 = i * 64 + lane;                // 16 B chunk id (256 total / 4 iters)
      int a = c2 >> 4, off = (c2 & 15) * 16; // atom, byte off in its 256 B half
      uint4 v = *(const uint4*)((const char*)T + ((a * 256 + off) ^ ((a & 7) << 4)));
      *(uint4*)(dst + a * 512 + off) = v;
    }
    wave_lds_fence();  // T reads retired before next-iter overwrite
    if (!hn) break;
    t = tn;
    // queue (oldest first): [ldh(t):8, stores(t-1):4] -> drain loads only
    asm volatile("s_waitcnt vmcnt(4)" ::: "memory");
  }
}

// ===================== janossy9: wave-specialized 4-stage pipeline ============
// R12 change: DEPTH-3 gather pipeline (was 2). Prologue issues 3 batches of
// {16 gathers + 4 idx} = 60 outstanding (vmcnt max 63); steady-state wait
// vmcnt(40) drains exactly batch b. Gathers now have 3 beats (~4.8 us) to
// land. Pre-committed read: unchanged duration => bandwidth-saturated.
__global__ __launch_bounds__(256, 2) void janossy9(
    const unsigned short* __restrict__ uv, const int* __restrict__ idx0,
    const int* __restrict__ idx1, const int* __restrict__ idx2,
    const int* __restrict__ idx3, const float* __restrict__ b2,
    const float* __restrict__ b3, const float* __restrict__ bo,
    const unsigned short* __restrict__ P, float* __restrict__ out) {
  __shared__ __attribute__((aligned(16))) unsigned short G[3][8192];   // 48 KB
  __shared__ __attribute__((aligned(16))) unsigned short RX[2][2048];  // 8 KB
  __shared__ __attribute__((aligned(16))) unsigned short RY[2][2048];  // 8 KB
  __shared__ __attribute__((aligned(16))) unsigned short RZ[2][2048];  // 8 KB

  const int lane = threadIdx.x & 63;
  const int wid = threadIdx.x >> 6;
  const int row = lane & 15, hi = lane >> 4;
  const int bk = blockIdx.x;
  const char* uvB = (const char*)uv;
  const unsigned int c16 = (unsigned int)(row * 16);

  f16x8 wfrag[32];
  float br[8] = {};
  float bov = 0.0f;
  if (wid == 0) {
#pragma unroll
    for (int ks = 0; ks < 4; ++ks)
      wfrag[ks] = *(const f16x8*)(P + PB1 + ks * 32 + hi * 8);  // b1 frags
  } else if (wid == 3) {
#pragma unroll
    for (int ks = 0; ks < 4; ++ks)
      wfrag[ks] = *(const f16x8*)(P + 65536 + row * 128 + ks * 32 + hi * 8);  // Wo
    bov = (row < 6) ? bo[row] : 0.0f;
  } else {
    const unsigned short* Wp = P + (wid == 1 ? 32768 : 49152);
    const float* bb = (wid == 1) ? b2 : b3;
#pragma unroll
    for (int n = 0; n < 8; ++n) {
      br[n] = bb[n * 16 + row];
#pragma unroll
      for (int ks = 0; ks < 4; ++ks)
        wfrag[n * 4 + ks] =
            *(const f16x8*)(Wp + (n * 16 + row) * 128 + ks * 32 + hi * 8);
    }
  }

  int jA[4][4], jB[4][4], jC[4][4];

#define LD_IDX(JJ, TILE)                                           \
  do {                                                             \
    int _t = (TILE); if (_t >= NT16) _t = 0;                       \
    int _r = _t * 16 + hi * 4;                                     \
    int4 _v0 = *(const int4*)(idx0 + _r);                          \
    int4 _v1 = *(const int4*)(idx1 + _r);                          \
    int4 _v2 = *(const int4*)(idx2 + _r);                          \
    int4 _v3 = *(const int4*)(idx3 + _r);                          \
    JJ[0][0] = _v0.x; JJ[1][0] = _v0.y; JJ[2][0] = _v0.z; JJ[3][0] = _v0.w; \
    JJ[0][1] = _v1.x; JJ[1][1] = _v1.y; JJ[2][1] = _v1.z; JJ[3][1] = _v1.w; \
    JJ[0][2] = _v2.x; JJ[1][2] = _v2.y; JJ[2][2] = _v2.z; JJ[3][2] = _v2.w; \
    JJ[0][3] = _v3.x; JJ[1][3] = _v3.y; JJ[2][3] = _v3.z; JJ[3][3] = _v3.w; \
  } while (0)

#define ISSUE_G(JJ, GBUF)                                                   \
  do {                                                                      \
    unsigned short* _gb = (GBUF);                                           \
    _Pragma("unroll") for (int g = 0; g < 4; ++g) {                         \
      const int grow = g * 4 + hi;                                          \
      const unsigned int colb = c16 ^ (unsigned int)((grow & 7) << 4);      \
      char* base = (char*)_gb + g * 1024;                                   \
      gload16(uvB + (long)JJ[g][0] * 512 + colb,       base);               \
      gload16(uvB + (long)JJ[g][2] * 512 + colb,       base + 4096);        \
      gload16(uvB + (long)JJ[g][3] * 512 + colb,       base + 8192);        \
      gload16(uvB + (long)JJ[g][1] * 512 + 256 + colb, base + 12288);       \
    }                                                                       \
  } while (0)

  if (wid == 0) {
    LD_IDX(jA, bk);
    LD_IDX(jB, bk + NBLK9);
    LD_IDX(jC, bk + 2 * NBLK9);
    asm volatile("s_waitcnt vmcnt(0)" ::: "memory");
    __builtin_amdgcn_sched_barrier(0);
    ISSUE_G(jA, G[0]);
    LD_IDX(jA, bk + 3 * NBLK9);
    ISSUE_G(jB, G[1]);
    LD_IDX(jB, bk + 4 * NBLK9);
    ISSUE_G(jC, G[2]);
    LD_IDX(jC, bk + 5 * NBLK9);
    // queue: 3 x [G:16, idx:4] = 60 outstanding
  }

#define BEAT(B, JJ)                                                            \
  do {                                                                         \
    const int _b = (B);                                                        \
    if (wid == 0) {                                                            \
      asm volatile("s_waitcnt vmcnt(40)" ::: "memory");                        \
      __builtin_amdgcn_sched_barrier(0);                                       \
      int t0 = bk + _b * NBLK9;                                                \
      if (t0 < NT16) {                                                         \
        const unsigned short* Gc = G[_b % 3];                                  \
        unsigned short* X = RX[_b & 1];                                        \
        _Pragma("unroll") for (int ks = 0; ks < 4; ++ks) {                     \
          int k0 = ks * 32 + hi * 8;                                           \
          f16x8 s = lds_frag(Gc, row, k0) + lds_frag(Gc + 2048, row, k0) +     \
                    lds_frag(Gc + 4096, row, k0) +                             \
                    lds_frag(Gc + 6144, row, k0) + wfrag[ks];                  \
          f16x8 z = {};                                                        \
          *(f16x8*)((char*)X + swz_off(row, k0 * 2)) =                         \
              __builtin_elementwise_max(s, z);                                 \
        }                                                                      \
      }                                                                        \
      wave_lds_fence(); /* G[_b%3] reads retired before DMA reuse */           \
      ISSUE_G(JJ, G[_b % 3]);                                                  \
      LD_IDX(JJ, bk + (_b + 6) * NBLK9);                                       \
    } else if (wid == 3) {                                                     \
      int t3 = bk + (_b - 3) * NBLK9;                                          \
      if (_b >= 3 && t3 < NT16) {                                              \
        const unsigned short* Z = RZ[(_b - 3) & 1];                            \
        f32x4 acch = {0.f, 0.f, 0.f, 0.f};                                     \
        _Pragma("unroll") for (int ks = 0; ks < 4; ++ks) {                     \
          int k0 = ks * 32 + hi * 8;                                           \
          f16x8 a = lds_frag(Z, row, k0);                                      \
          acch = __builtin_amdgcn_mfma_f32_16x16x32_f16(a, wfrag[ks], acch,    \
                                                        0, 0, 0);              \
        }                                                                      \
        if (row < 6) {                                                         \
          float* ob = out + (long)t3 * 96;                                     \
          _Pragma("unroll") for (int r = 0; r < 4; ++r)                        \
            ob[(r * 4 + hi) * 6 + row] = acch[r] + bov;                        \
        }                                                                      \
      }                                                                        \
    } else {                                                                   \
      int th = bk + (_b - wid) * NBLK9;                                        \
      if (_b >= wid && th < NT16) {                                            \
        const unsigned short* inb =                                            \
            (wid == 1) ? RX[(_b - 1) & 1] : RY[(_b - 2) & 1];                  \
        unsigned short* outb =                                                 \
            (wid == 1) ? RY[(_b - 1) & 1] : RZ[(_b - 2) & 1];                  \
        f32x4 acc[8] = {};                                                     \
        _Pragma("unroll") for (int ks = 0; ks < 4; ++ks) {                     \
          int k0 = ks * 32 + hi * 8;                                           \
          f16x8 a = lds_frag(inb, row, k0);                                    \
          _Pragma("unroll") for (int n = 0; n < 8; ++n)                        \
            acc[n] = __builtin_amdgcn_mfma_f32_16x16x32_f16(                   \
                a, wfrag[n * 4 + ks], acc[n], 0, 0, 0);                        \
        }                                                                      \
        _Pragma("unroll") for (int n = 0; n < 8; ++n) {                        \
          int col = n * 16 + row;                                              \
          _Pragma("unroll") for (int r = 0; r < 4; ++r) {                      \
            float v = fmaxf(acc[n][r] + br[n], 0.0f);                          \
            lds_st1(outb, hi * 4 + r, col, f2h(v));                            \
          }                                                                    \
        }                                                                      \
      }                                                                        \
    }                                                                          \
    __syncthreads();                                                           \
  } while (0)

  for (int b = 0; b < NBEATS9; b += 3) {
    BEAT(b, jA);
    BEAT(b + 1, jB);
    BEAT(b + 2, jC);
  }
  if (wid == 0) asm volatile("s_waitcnt vmcnt(0)" ::: "memory");
#undef BEAT
#undef ISSUE_G
#undef LD_IDX
}

// ===================== fallback path (R1, needs only 136 KB ws) =====================

__device__ __forceinline__ void lds_st4(unsigned short* buf, int row, int k0,
                                        float a, float b, float c, float d) {
  uint2 u; u.x = pk2(a, b); u.y = pk2(c, d);
  *(uint2*)((char*)buf + swz_off(row, k0 * 2)) = u;
}

template <bool DUAL>
__device__ __forceinline__ void mlp_layer(
    const unsigned short* A1, const unsigned short* __restrict__ B1,
    const unsigned short* A2, const unsigned short* __restrict__ B2,
    const float* __restrict__ bias, unsigned short* Obuf, int lane, int wr, int wc) {
  f32x4 acc[2][4] = {};
#pragma unroll
  for (int ks = 0; ks < 4; ++ks) {
    int k0 = ks * 32 + (lane >> 4) * 8;
    f16x8 a0 = lds_frag(A1, wr * 32 + (lane & 15), k0);
    f16x8 a1 = lds_frag(A1, wr * 32 + 16 + (lane & 15), k0);
#pragma unroll
    for (int n = 0; n < 4; ++n) {
      int col = wc * 64 + n * 16 + (lane & 15);
      f16x8 b = *(const f16x8*)(B1 + col * 128 + k0);
      acc[0][n] = __builtin_amdgcn_mfma_f32_16x16x32_f16(a0, b, acc[0][n], 0, 0, 0);
      acc[1][n] = __builtin_amdgcn_mfma_f32_16x16x32_f16(a1, b, acc[1][n], 0, 0, 0);
    }
  }
  if constexpr (DUAL) {
#pragma unroll
    for (int ks = 0; ks < 4; ++ks) {
      int k0 = ks * 32 + (lane >> 4) * 8;
      f16x8 a0 = lds_frag(A2, wr * 32 + (lane & 15), k0);
      f16x8 a1 = lds_frag(A2, wr * 32 + 16 + (lane & 15), k0);
#pragma unroll
      for (int n = 0; n < 4; ++n) {
        int col = wc * 64 + n * 16 + (lane & 15);
        f16x8 b = *(const f16x8*)(B2 + col * 128 + k0);
        acc[0][n] = __builtin_amdgcn_mfma_f32_16x16x32_f16(a0, b, acc[0][n], 0, 0, 0);
        acc[1][n] = __builtin_amdgcn_mfma_f32_16x16x32_f16(a1, b, acc[1][n], 0, 0, 0);
      }
    }
  }
#pragma unroll
  for (int n = 0; n < 4; ++n) {
    int col = wc * 64 + n * 16 + (lane & 15);
    float bn = bias[col];
#pragma unroll
    for (int m = 0; m < 2; ++m) {
#pragma unroll
      for (int r = 0; r < 4; ++r) {
        float v = fmaxf(acc[m][n][r] + bn, 0.0f);
        lds_st1(Obuf, wr * 32 + m * 16 + (lane >> 4) * 4 + r, col, f2h(v));
      }
    }
  }
}

__global__ __launch_bounds__(256) void janossy_kernel(
    const float* __restrict__ h, const int* __restrict__ idx0,
    const int* __restrict__ idx1, const int* __restrict__ idx2,
    const int* __restrict__ idx3, const float* __restrict__ b1,
    const float* __restrict__ b2, const float* __restrict__ b3,
    const float* __restrict__ bo, const unsigned short* __restrict__ P,
    float* __restrict__ out) {
  __shared__ __attribute__((aligned(16))) unsigned short sA[64 * 128];
  __shared__ __attribute__((aligned(16))) unsigned short tA[64 * 128];
  __shared__ __attribute__((aligned(16))) unsigned short xA[64 * 128];
  const int tid = threadIdx.x;
  const int lane = tid & 63;
  const int wid = tid >> 6;
  const int wr = wid & 1, wc = wid >> 1;
  const int blk = blockIdx.x;
  {
    int row = tid >> 2, q = tid & 3;
    int rg = blk * 64 + row;
    if (rg < N_IMP) {
      const float4* p0 = (const float4*)h + (long)idx0[rg] * 32 + q * 8;
      const float4* p1 = (const float4*)h + (long)idx1[rg] * 32 + q * 8;
      const float4* p2 = (const float4*)h + (long)idx2[rg] * 32 + q * 8;
      const float4* p3 = (const float4*)h + (long)idx3[rg] * 32 + q * 8;
#pragma unroll
      for (int c = 0; c < 8; ++c) {
        float4 v0 = p0[c], v1 = p1[c], v2 = p2[c], v3 = p3[c];
        int k0 = q * 32 + c * 4;
        lds_st4(sA, row, k0, v0.x + v2.x + v3.x, v0.y + v2.y + v3.y,
                v0.z + v2.z + v3.z, v0.w + v2.w + v3.w);
        lds_st4(tA, row, k0, v1.x, v1.y, v1.z, v1.w);
      }
    } else {
#pragma unroll
      for (int c = 0; c < 8; ++c) {
        int k0 = q * 32 + c * 4;
        lds_st4(sA, row, k0, 0.f, 0.f, 0.f, 0.f);
        lds_st4(tA, row, k0, 0.f, 0.f, 0.f, 0.f);
      }
    }
  }
  __syncthreads();
  mlp_layer<true>(sA, P, tA, P + 16384, b1, xA, lane, wr, wc);
  __syncthreads();
  mlp_layer<false>(xA, P + 32768, nullptr, nullptr, b2, sA, lane, wr, wc);
  __syncthreads();
  mlp_layer<false>(sA, P + 49152, nullptr, nullptr, b3, tA, lane, wr, wc);
  __syncthreads();
  {
    f32x4 acc = {0.f, 0.f, 0.f, 0.f};
#pragma unroll
    for (int ks = 0; ks < 4; ++ks) {
      int k0 = ks * 32 + (lane >> 4) * 8;
      f16x8 a = lds_frag(tA, wid * 16 + (lane & 15), k0);
      f16x8 b = *(const f16x8*)(P + 65536 + (lane & 15) * 128 + k0);
      acc = __builtin_amdgcn_mfma_f32_16x16x32_f16(a, b, acc, 0, 0, 0);
    }
    int col = lane & 15;
    if (col < 6) {
      float bov = bo[col];
#pragma unroll
      for (int r = 0; r < 4; ++r) {
        int rg = blk * 64 + wid * 16 + (lane >> 4) * 4 + r;
        if (rg < N_IMP) out[rg * 6 + col] = acc[r] + bov;
      }
    }
  }
}

extern "C" void kernel_launch(void* const* d_in, const int* in_sizes, int n_in,
                              void* d_out, int out_size, void* d_ws, size_t ws_size,
                              hipStream_t stream) {
  const float* h   = (const float*)d_in[0];
  const int* idx0  = (const int*)d_in[1];
  const int* idx1  = (const int*)d_in[2];
  const int* idx2  = (const int*)d_in[3];
  const int* idx3  = (const int*)d_in[4];
  const float* W1  = (const float*)d_in[5];
  const float* b1  = (const float*)d_in[6];
  const float* W2  = (const float*)d_in[7];
  const float* b2  = (const float*)d_in[8];
  const float* W3  = (const float*)d_in[9];
  const float* b3  = (const float*)d_in[10];
  const float* Wo  = (const float*)d_in[11];
  const float* bo  = (const float*)d_in[12];
  float* out = (float*)d_out;
  unsigned short* P = (unsigned short*)d_ws;

  prep_kernel<<<dim3(265), dim3(256), 0, stream>>>(W1, W2, W3, Wo, b1, P);
  if (ws_size >= WS_NEED) {
    unsigned short* uv = P + UV_OFF;
    atom_gemm4<<<dim3(NBLKA), dim3(256), 0, stream>>>(h, P, uv);
    janossy9<<<dim3(NBLK9), dim3(256), 0, stream>>>(
        uv, idx0, idx1, idx2, idx3, b2, b3, bo, P, out);
  } else {
    janossy_kernel<<<dim3((N_IMP + 63) / 64), dim3(256), 0, stream>>>(
        h, idx0, idx1, idx2, idx3, b1, b2, b3, bo, P, out);
  }
}

// Round 13
// 91.724 us; speedup vs baseline: 1.4408x; 1.4408x over previous
//
#include <hip/hip_runtime.h>

typedef _Float16 f16x8 __attribute__((ext_vector_type(8)));
typedef float f32x4 __attribute__((ext_vector_type(4)));

#define N_IMP 300000
#define N_ATOMS 100000
#define NT16 (N_IMP / 16)        // 18750 16-row tiles
#define AT_TILES (N_ATOMS / 16)  // 6250
#define NBLK9 512                // janossy9 blocks (2 per CU)
#define NBEATS9 40               // ceil(18750/512)=37 tiles/block max + 3 drain
#define NBLKA 512                // atom_gemm4 blocks; 2 tile-pairs each

__device__ __forceinline__ unsigned short f2h(float f) {
  _Float16 h = (_Float16)f;  // v_cvt_f16_f32, RNE
  return __builtin_bit_cast(unsigned short, h);
}
__device__ __forceinline__ unsigned int pk2(float a, float b) {
  return (unsigned int)f2h(a) | ((unsigned int)f2h(b) << 16);
}

// Packed f16 weights in d_ws (ushort units):
//  [0,16384)      Wa  [n][k]  = W1[0:128] + W1[256:384] + W1[384:512]
//  [16384,32768)  Wb  [n][k]  = 3*W1[128:256]
//  [32768,49152)  W2p [n][k]
//  [49152,65536)  W3p [n][k]
//  [65536,67584)  Wop [16][128] (cols 6..15 zero)
//  [67584,67712)  b1 as f16 (128)
//  [67712, +25.6M) uv [atom][256] f16: u = h@Wa (0:128), v = h@Wb (128:256)
#define PB1 67584
#define UV_OFF 67712
#define WS_NEED (2ull * (UV_OFF + (unsigned long long)N_ATOMS * 256))

__global__ __launch_bounds__(256) void prep_kernel(
    const float* __restrict__ W1, const float* __restrict__ W2,
    const float* __restrict__ W3, const float* __restrict__ Wo,
    const float* __restrict__ b1, unsigned short* __restrict__ P) {
  int t = blockIdx.x * 256 + threadIdx.x;  // grid 265 blocks = 67840 threads
  if (t >= UV_OFF) return;
  float v;
  if (t < 16384) {
    int n = t >> 7, k = t & 127;
    v = W1[k * 128 + n] + W1[(k + 256) * 128 + n] + W1[(k + 384) * 128 + n];
  } else if (t < 32768) {
    int i = t - 16384; int n = i >> 7, k = i & 127;
    v = 3.0f * W1[(k + 128) * 128 + n];
  } else if (t < 49152) {
    int i = t - 32768; int n = i >> 7, k = i & 127;
    v = W2[k * 128 + n];
  } else if (t < 65536) {
    int i = t - 49152; int n = i >> 7, k = i & 127;
    v = W3[k * 128 + n];
  } else if (t < PB1) {
    int i = t - 65536; int n = i >> 7, k = i & 127;
    v = (n < 6) ? Wo[k * 6 + n] : 0.0f;
  } else {
    v = b1[t - PB1];
  }
  P[t] = f2h(v);
}

// XOR-swizzled row layout, stride 256 B (G4: row-major 256B-stride f16 is a
// 16-way bank conflict on ds_read_b128 without it). Involution on writer side
// (pre-swizzled global source for gathers / swizzled ds_write) and reader
// side (rule #21). XOR of bit 4 preserves 16B alignment.
__device__ __forceinline__ int swz_off(int row, int kbyte) {
  return (row * 256 + kbyte) ^ ((row & 7) << 4);
}
__device__ __forceinline__ f16x8 lds_frag(const unsigned short* buf, int row, int k0) {
  return *(const f16x8*)((const char*)buf + swz_off(row, k0 * 2));
}
__device__ __forceinline__ void lds_st1(unsigned short* buf, int row, int col, unsigned short v) {
  *(unsigned short*)((char*)buf + swz_off(row, col * 2)) = v;
}
__device__ __forceinline__ void wave_lds_fence() {
  asm volatile("s_waitcnt lgkmcnt(0)" ::: "memory");
}
// Direct global->LDS (no VGPR round-trip). LDS dest = wave-uniform base +
// lane*16; global src is per-lane.
__device__ __forceinline__ void gload16(const void* g, void* l) {
  __builtin_amdgcn_global_load_lds(
      (const __attribute__((address_space(1))) unsigned int*)g,
      (__attribute__((address_space(3))) unsigned int*)l, 16, 0, 0);
}

// ======== atom precompute v4: uv = [h@Wa | h@Wb], weights in REGISTERS ========
// Weights held in 128 loop-invariant VGPRs; h(t+1) loads fly under tile t's
// compute. Loop-top vmcnt(4) lets trailing uv stores linger (compiler's
// auto-inserted waits before hv use guarantee correctness regardless).
__global__ __launch_bounds__(256, 2) void atom_gemm4(
    const float* __restrict__ h, const unsigned short* __restrict__ P,
    unsigned short* __restrict__ uv) {
  __shared__ __attribute__((aligned(16))) unsigned short Tb[4][2048];  // 4 KB/wave
  const int lane = threadIdx.x & 63;
  const int wid = threadIdx.x >> 6;
  const int col = lane & 15, hi = lane >> 4;
  const int p = wid & 1;  // feature half
  unsigned short* T = Tb[wid];

  // loop-invariant A-frags: feats (p*8+n)*16+col, k = ks*32+hi*8
  f16x8 wfa[32];
#pragma unroll
  for (int n = 0; n < 8; ++n)
#pragma unroll
    for (int ks = 0; ks < 4; ++ks)
      wfa[n * 4 + ks] =
          *(const f16x8*)(P + ((p * 8 + n) * 16 + col) * 128 + ks * 32 + hi * 8);

  float4 hv[8];
  auto ldh = [&](int tt) {
    const float4* phv = (const float4*)(h + (long)(tt * 16 + col) * 128);
#pragma unroll
    for (int ks = 0; ks < 4; ++ks) {
      hv[ks * 2]     = phv[ks * 8 + hi * 2];
      hv[ks * 2 + 1] = phv[ks * 8 + hi * 2 + 1];
    }
  };

  int t = blockIdx.x * 2 + (wid >> 1);  // tile id, stride NBLKA*2 = 1024
  ldh(t);
  asm volatile("s_waitcnt vmcnt(0)" ::: "memory");  // prologue: hv(t0) landed
  for (;;) {
    const int tn = t + NBLKA * 2;
    const bool hn = (tn < AT_TILES);  // wave-uniform
    __builtin_amdgcn_sched_barrier(0);
    f16x8 bfr[4];
#pragma unroll
    for (int ks = 0; ks < 4; ++ks) {
      float4 v0 = hv[ks * 2], v1 = hv[ks * 2 + 1];
      f16x8 b;
      b[0] = (_Float16)v0.x; b[1] = (_Float16)v0.y; b[2] = (_Float16)v0.z; b[3] = (_Float16)v0.w;
      b[4] = (_Float16)v1.x; b[5] = (_Float16)v1.y; b[6] = (_Float16)v1.z; b[7] = (_Float16)v1.w;
      bfr[ks] = b;
    }
    if (hn) ldh(tn);  // fly under MFMA + transpose + store

    f32x4 acc[8] = {};
#pragma unroll
    for (int ks = 0; ks < 4; ++ks)
#pragma unroll
      for (int n = 0; n < 8; ++n)
        acc[n] = __builtin_amdgcn_mfma_f32_16x16x32_f16(wfa[n * 4 + ks], bfr[ks],
                                                        acc[n], 0, 0, 0);

    // transpose: D(col=atom, feat=n*16+hi*4+r) -> T[atom][128 feats-half],
    // row stride 256 B, XOR bit4..6 with atom&7 (8B writes -> 2-way max).
#pragma unroll
    for (int n = 0; n < 8; ++n) {
      uint2 w; w.x = pk2(acc[n][0], acc[n][1]); w.y = pk2(acc[n][2], acc[n][3]);
      int bo_ = (col * 256 + n * 32 + hi * 8) ^ ((col & 7) << 4);
      *(uint2*)((char*)T + bo_) = w;
    }
    wave_lds_fence();
    // readback linear (same involution) -> 256 B contiguous per atom-half
    char* dst = (char*)uv + (long)t * 16 * 512 + p * 256;
#pragma unroll
    for (int i = 0; i < 4; ++i) {
      int c2 = i * 64 + lane;                // 16 B chunk id (256 total / 4 iters)
      int a = c2 >> 4, off = (c2 & 15) * 16; // atom, byte off in its 256 B half
      uint4 v = *(const uint4*)((const char*)T + ((a * 256 + off) ^ ((a & 7) << 4)));
      *(uint4*)(dst + a * 512 + off) = v;
    }
    wave_lds_fence();  // T reads retired before next-iter overwrite
    if (!hn) break;
    t = tn;
    asm volatile("s_waitcnt vmcnt(4)" ::: "memory");
  }
}

// ===================== janossy9: wave-specialized 4-stage pipeline ============
// REVERTED to the R11 depth-2 version (64 us): depth-3 (R12) regressed to
// 108 us — 60 outstanding DMA/wave degraded delivered BW (queueing past
// saturation) and the immediate-reuse fence serialized w0's beat. Depth-2 is
// the measured operating point.
__global__ __launch_bounds__(256, 2) void janossy9(
    const unsigned short* __restrict__ uv, const int* __restrict__ idx0,
    const int* __restrict__ idx1, const int* __restrict__ idx2,
    const int* __restrict__ idx3, const float* __restrict__ b2,
    const float* __restrict__ b3, const float* __restrict__ bo,
    const unsigned short* __restrict__ P, float* __restrict__ out) {
  __shared__ __attribute__((aligned(16))) unsigned short G[3][8192];   // 48 KB
  __shared__ __attribute__((aligned(16))) unsigned short RX[2][2048];  // 8 KB
  __shared__ __attribute__((aligned(16))) unsigned short RY[2][2048];  // 8 KB
  __shared__ __attribute__((aligned(16))) unsigned short RZ[2][2048];  // 8 KB

  const int lane = threadIdx.x & 63;
  const int wid = threadIdx.x >> 6;
  const int row = lane & 15, hi = lane >> 4;
  const int bk = blockIdx.x;
  const char* uvB = (const char*)uv;
  const unsigned int c16 = (unsigned int)(row * 16);

  f16x8 wfrag[32];
  float br[8] = {};
  float bov = 0.0f;
  if (wid == 0) {
#pragma unroll
    for (int ks = 0; ks < 4; ++ks)
      wfrag[ks] = *(const f16x8*)(P + PB1 + ks * 32 + hi * 8);  // b1 frags
  } else if (wid == 3) {
#pragma unroll
    for (int ks = 0; ks < 4; ++ks)
      wfrag[ks] = *(const f16x8*)(P + 65536 + row * 128 + ks * 32 + hi * 8);  // Wo
    bov = (row < 6) ? bo[row] : 0.0f;
  } else {
    const unsigned short* Wp = P + (wid == 1 ? 32768 : 49152);
    const float* bb = (wid == 1) ? b2 : b3;
#pragma unroll
    for (int n = 0; n < 8; ++n) {
      br[n] = bb[n * 16 + row];
#pragma unroll
      for (int ks = 0; ks < 4; ++ks)
        wfrag[n * 4 + ks] =
            *(const f16x8*)(Wp + (n * 16 + row) * 128 + ks * 32 + hi * 8);
    }
  }

  int jA[4][4], jB[4][4];

#define LD_IDX(JJ, TILE)                                           \
  do {                                                             \
    int _t = (TILE); if (_t >= NT16) _t = 0;                       \
    int _r = _t * 16 + hi * 4;                                     \
    int4 _v0 = *(const int4*)(idx0 + _r);                          \
    int4 _v1 = *(const int4*)(idx1 + _r);                          \
    int4 _v2 = *(const int4*)(idx2 + _r);                          \
    int4 _v3 = *(const int4*)(idx3 + _r);                          \
    JJ[0][0] = _v0.x; JJ[1][0] = _v0.y; JJ[2][0] = _v0.z; JJ[3][0] = _v0.w; \
    JJ[0][1] = _v1.x; JJ[1][1] = _v1.y; JJ[2][1] = _v1.z; JJ[3][1] = _v1.w; \
    JJ[0][2] = _v2.x; JJ[1][2] = _v2.y; JJ[2][2] = _v2.z; JJ[3][2] = _v2.w; \
    JJ[0][3] = _v3.x; JJ[1][3] = _v3.y; JJ[2][3] = _v3.z; JJ[3][3] = _v3.w; \
  } while (0)

#define ISSUE_G(JJ, GBUF)                                                   \
  do {                                                                      \
    unsigned short* _gb = (GBUF);                                           \
    _Pragma("unroll") for (int g = 0; g < 4; ++g) {                         \
      const int grow = g * 4 + hi;                                          \
      const unsigned int colb = c16 ^ (unsigned int)((grow & 7) << 4);      \
      char* base = (char*)_gb + g * 1024;                                   \
      gload16(uvB + (long)JJ[g][0] * 512 + colb,       base);               \
      gload16(uvB + (long)JJ[g][2] * 512 + colb,       base + 4096);        \
      gload16(uvB + (long)JJ[g][3] * 512 + colb,       base + 8192);        \
      gload16(uvB + (long)JJ[g][1] * 512 + 256 + colb, base + 12288);       \
    }                                                                       \
  } while (0)

  if (wid == 0) {
    LD_IDX(jA, bk);
    LD_IDX(jB, bk + NBLK9);
    asm volatile("s_waitcnt vmcnt(0)" ::: "memory");
    __builtin_amdgcn_sched_barrier(0);
    ISSUE_G(jA, G[0]);
    LD_IDX(jA, bk + 2 * NBLK9);
    ISSUE_G(jB, G[1]);
    LD_IDX(jB, bk + 3 * NBLK9);
    // queue: [G(0):16, idxA:4, G(1):16, idxB:4] = 40 outstanding
  }

#define BEAT(B, JJ)                                                            \
  do {                                                                         \
    const int _b = (B);                                                        \
    if (wid == 0) {                                                            \
      asm volatile("s_waitcnt vmcnt(20)" ::: "memory");                        \
      __builtin_amdgcn_sched_barrier(0);                                       \
      int t0 = bk + _b * NBLK9;                                                \
      if (t0 < NT16) {                                                         \
        const unsigned short* Gc = G[_b % 3];                                  \
        unsigned short* X = RX[_b & 1];                                        \
        _Pragma("unroll") for (int ks = 0; ks < 4; ++ks) {                     \
          int k0 = ks * 32 + hi * 8;                                           \
          f16x8 s = lds_frag(Gc, row, k0) + lds_frag(Gc + 2048, row, k0) +     \
                    lds_frag(Gc + 4096, row, k0) +                             \
                    lds_frag(Gc + 6144, row, k0) + wfrag[ks];                  \
          f16x8 z = {};                                                        \
          *(f16x8*)((char*)X + swz_off(row, k0 * 2)) =                         \
              __builtin_elementwise_max(s, z);                                 \
        }                                                                      \
      }                                                                        \
      ISSUE_G(JJ, G[(_b + 2) % 3]);                                            \
      LD_IDX(JJ, bk + (_b + 4) * NBLK9);                                       \
    } else if (wid == 3) {                                                     \
      int t3 = bk + (_b - 3) * NBLK9;                                          \
      if (_b >= 3 && t3 < NT16) {                                              \
        const unsigned short* Z = RZ[(_b - 3) & 1];                            \
        f32x4 acch = {0.f, 0.f, 0.f, 0.f};                                     \
        _Pragma("unroll") for (int ks = 0; ks < 4; ++ks) {                     \
          int k0 = ks * 32 + hi * 8;                                           \
          f16x8 a = lds_frag(Z, row, k0);                                      \
          acch = __builtin_amdgcn_mfma_f32_16x16x32_f16(a, wfrag[ks], acch,    \
                                                        0, 0, 0);              \
        }                                                                      \
        if (row < 6) {                                                         \
          float* ob = out + (long)t3 * 96;                                     \
          _Pragma("unroll") for (int r = 0; r < 4; ++r)                        \
            ob[(r * 4 + hi) * 6 + row] = acch[r] + bov;                        \
        }                                                                      \
      }                                                                        \
    } else {                                                                   \
      int th = bk + (_b - wid) * NBLK9;                                        \
      if (_b >= wid && th < NT16) {                                            \
        const unsigned short* inb =                                            \
            (wid == 1) ? RX[(_b - 1) & 1] : RY[(_b - 2) & 1];                  \
        unsigned short* outb =                                                 \
            (wid == 1) ? RY[(_b - 1) & 1] : RZ[(_b - 2) & 1];                  \
        f32x4 acc[8] = {};                                                     \
        _Pragma("unroll") for (int ks = 0; ks < 4; ++ks) {                     \
          int k0 = ks * 32 + hi * 8;                                           \
          f16x8 a = lds_frag(inb, row, k0);                                    \
          _Pragma("unroll") for (int n = 0; n < 8; ++n)                        \
            acc[n] = __builtin_amdgcn_mfma_f32_16x16x32_f16(                   \
                a, wfrag[n * 4 + ks], acc[n], 0, 0, 0);                        \
        }                                                                      \
        _Pragma("unroll") for (int n = 0; n < 8; ++n) {                        \
          int col = n * 16 + row;                                              \
          _Pragma("unroll") for (int r = 0; r < 4; ++r) {                      \
            float v = fmaxf(acc[n][r] + br[n], 0.0f);                          \
            lds_st1(outb, hi * 4 + r, col, f2h(v));                            \
          }                                                                    \
        }                                                                      \
      }                                                                        \
    }                                                                          \
    __syncthreads();                                                           \
  } while (0)

  for (int b = 0; b < NBEATS9; b += 2) {
    BEAT(b, jA);
    BEAT(b + 1, jB);
  }
  if (wid == 0) asm volatile("s_waitcnt vmcnt(0)" ::: "memory");
#undef BEAT
#undef ISSUE_G
#undef LD_IDX
}

// ===================== fallback path (R1, needs only 136 KB ws) =====================

__device__ __forceinline__ void lds_st4(unsigned short* buf, int row, int k0,
                                        float a, float b, float c, float d) {
  uint2 u; u.x = pk2(a, b); u.y = pk2(c, d);
  *(uint2*)((char*)buf + swz_off(row, k0 * 2)) = u;
}

template <bool DUAL>
__device__ __forceinline__ void mlp_layer(
    const unsigned short* A1, const unsigned short* __restrict__ B1,
    const unsigned short* A2, const unsigned short* __restrict__ B2,
    const float* __restrict__ bias, unsigned short* Obuf, int lane, int wr, int wc) {
  f32x4 acc[2][4] = {};
#pragma unroll
  for (int ks = 0; ks < 4; ++ks) {
    int k0 = ks * 32 + (lane >> 4) * 8;
    f16x8 a0 = lds_frag(A1, wr * 32 + (lane & 15), k0);
    f16x8 a1 = lds_frag(A1, wr * 32 + 16 + (lane & 15), k0);
#pragma unroll
    for (int n = 0; n < 4; ++n) {
      int col = wc * 64 + n * 16 + (lane & 15);
      f16x8 b = *(const f16x8*)(B1 + col * 128 + k0);
      acc[0][n] = __builtin_amdgcn_mfma_f32_16x16x32_f16(a0, b, acc[0][n], 0, 0, 0);
      acc[1][n] = __builtin_amdgcn_mfma_f32_16x16x32_f16(a1, b, acc[1][n], 0, 0, 0);
    }
  }
  if constexpr (DUAL) {
#pragma unroll
    for (int ks = 0; ks < 4; ++ks) {
      int k0 = ks * 32 + (lane >> 4) * 8;
      f16x8 a0 = lds_frag(A2, wr * 32 + (lane & 15), k0);
      f16x8 a1 = lds_frag(A2, wr * 32 + 16 + (lane & 15), k0);
#pragma unroll
      for (int n = 0; n < 4; ++n) {
        int col = wc * 64 + n * 16 + (lane & 15);
        f16x8 b = *(const f16x8*)(B2 + col * 128 + k0);
        acc[0][n] = __builtin_amdgcn_mfma_f32_16x16x32_f16(a0, b, acc[0][n], 0, 0, 0);
        acc[1][n] = __builtin_amdgcn_mfma_f32_16x16x32_f16(a1, b, acc[1][n], 0, 0, 0);
      }
    }
  }
#pragma unroll
  for (int n = 0; n < 4; ++n) {
    int col = wc * 64 + n * 16 + (lane & 15);
    float bn = bias[col];
#pragma unroll
    for (int m = 0; m < 2; ++m) {
#pragma unroll
      for (int r = 0; r < 4; ++r) {
        float v = fmaxf(acc[m][n][r] + bn, 0.0f);
        lds_st1(Obuf, wr * 32 + m * 16 + (lane >> 4) * 4 + r, col, f2h(v));
      }
    }
  }
}

__global__ __launch_bounds__(256) void janossy_kernel(
    const float* __restrict__ h, const int* __restrict__ idx0,
    const int* __restrict__ idx1, const int* __restrict__ idx2,
    const int* __restrict__ idx3, const float* __restrict__ b1,
    const float* __restrict__ b2, const float* __restrict__ b3,
    const float* __restrict__ bo, const unsigned short* __restrict__ P,
    float* __restrict__ out) {
  __shared__ __attribute__((aligned(16))) unsigned short sA[64 * 128];
  __shared__ __attribute__((aligned(16))) unsigned short tA[64 * 128];
  __shared__ __attribute__((aligned(16))) unsigned short xA[64 * 128];
  const int tid = threadIdx.x;
  const int lane = tid & 63;
  const int wid = tid >> 6;
  const int wr = wid & 1, wc = wid >> 1;
  const int blk = blockIdx.x;
  {
    int row = tid >> 2, q = tid & 3;
    int rg = blk * 64 + row;
    if (rg < N_IMP) {
      const float4* p0 = (const float4*)h + (long)idx0[rg] * 32 + q * 8;
      const float4* p1 = (const float4*)h + (long)idx1[rg] * 32 + q * 8;
      const float4* p2 = (const float4*)h + (long)idx2[rg] * 32 + q * 8;
      const float4* p3 = (const float4*)h + (long)idx3[rg] * 32 + q * 8;
#pragma unroll
      for (int c = 0; c < 8; ++c) {
        float4 v0 = p0[c], v1 = p1[c], v2 = p2[c], v3 = p3[c];
        int k0 = q * 32 + c * 4;
        lds_st4(sA, row, k0, v0.x + v2.x + v3.x, v0.y + v2.y + v3.y,
                v0.z + v2.z + v3.z, v0.w + v2.w + v3.w);
        lds_st4(tA, row, k0, v1.x, v1.y, v1.z, v1.w);
      }
    } else {
#pragma unroll
      for (int c = 0; c < 8; ++c) {
        int k0 = q * 32 + c * 4;
        lds_st4(sA, row, k0, 0.f, 0.f, 0.f, 0.f);
        lds_st4(tA, row, k0, 0.f, 0.f, 0.f, 0.f);
      }
    }
  }
  __syncthreads();
  mlp_layer<true>(sA, P, tA, P + 16384, b1, xA, lane, wr, wc);
  __syncthreads();
  mlp_layer<false>(xA, P + 32768, nullptr, nullptr, b2, sA, lane, wr, wc);
  __syncthreads();
  mlp_layer<false>(sA, P + 49152, nullptr, nullptr, b3, tA, lane, wr, wc);
  __syncthreads();
  {
    f32x4 acc = {0.f, 0.f, 0.f, 0.f};
#pragma unroll
    for (int ks = 0; ks < 4; ++ks) {
      int k0 = ks * 32 + (lane >> 4) * 8;
      f16x8 a = lds_frag(tA, wid * 16 + (lane & 15), k0);
      f16x8 b = *(const f16x8*)(P + 65536 + (lane & 15) * 128 + k0);
      acc = __builtin_amdgcn_mfma_f32_16x16x32_f16(a, b, acc, 0, 0, 0);
    }
    int col = lane & 15;
    if (col < 6) {
      float bov = bo[col];
#pragma unroll
      for (int r = 0; r < 4; ++r) {
        int rg = blk * 64 + wid * 16 + (lane >> 4) * 4 + r;
        if (rg < N_IMP) out[rg * 6 + col] = acc[r] + bov;
      }
    }
  }
}

extern "C" void kernel_launch(void* const* d_in, const int* in_sizes, int n_in,
                              void* d_out, int out_size, void* d_ws, size_t ws_size,
                              hipStream_t stream) {
  const float* h   = (const float*)d_in[0];
  const int* idx0  = (const int*)d_in[1];
  const int* idx1  = (const int*)d_in[2];
  const int* idx2  = (const int*)d_in[3];
  const int* idx3  = (const int*)d_in[4];
  const float* W1  = (const float*)d_in[5];
  const float* b1  = (const float*)d_in[6];
  const float* W2  = (const float*)d_in[7];
  const float* b2  = (const float*)d_in[8];
  const float* W3  = (const float*)d_in[9];
  const float* b3  = (const float*)d_in[10];
  const float* Wo  = (const float*)d_in[11];
  const float* bo  = (const float*)d_in[12];
  float* out = (float*)d_out;
  unsigned short* P = (unsigned short*)d_ws;

  prep_kernel<<<dim3(265), dim3(256), 0, stream>>>(W1, W2, W3, Wo, b1, P);
  if (ws_size >= WS_NEED) {
    unsigned short* uv = P + UV_OFF;
    atom_gemm4<<<dim3(NBLKA), dim3(256), 0, stream>>>(h, P, uv);
    janossy9<<<dim3(NBLK9), dim3(256), 0, stream>>>(
        uv, idx0, idx1, idx2, idx3, b2, b3, bo, P, out);
  } else {
    janossy_kernel<<<dim3((N_IMP + 63) / 64), dim3(256), 0, stream>>>(
        h, idx0, idx1, idx2, idx3, b1, b2, b3, bo, P, out);
  }
}